// Round 1
// baseline (586.788 us; speedup 1.0000x reference)
//
#include <hip/hip_runtime.h>

// GridEncoder (instant-NGP style triplane hash grid), static config:
//   D=3, L=3 levels, C=2, base_res=128, per_level_scale=2, hashmap=2^19,
//   align_corners=False, linear interp, B=2^21 points.
// Key derived facts (see reference):
//   - every level uses HASH indexing (stride_dim^3 > 2^19 always)
//   - hmap = 2^19 for all levels -> mod is & 0x7FFFF
//   - offsets[l] = l * 2^19 and 2^19 == 1024*512, so level l gathers from
//     plane l of the triplane. With the permute(0,2,3,1) flatten,
//     emb[idx][c] == triplane_flat[l*1048576 + c*524288 + (idx & 0x7FFFF)]

#define NPOINTS 2097152
#define HMASK   0x7FFFFu
#define PLANE   524288   // elements per (level, channel) slice

__global__ __launch_bounds__(256) void GridEncoder_74234214744826_kernel(
    const float* __restrict__ triplane,  // [3,2,1024,512] flat
    const float* __restrict__ inputs,    // [B,3]
    float* __restrict__ out)             // [B,2]
{
    const int i = blockIdx.x * blockDim.x + threadIdx.x;
    if (i >= NPOINTS) return;

    const float x = inputs[3 * i + 0];
    const float y = inputs[3 * i + 1];
    const float z = inputs[3 * i + 2];

    // x01 = (x + 1) / 2
    const float x0 = (x + 1.0f) * 0.5f;
    const float y0 = (y + 1.0f) * 0.5f;
    const float z0 = (z + 1.0f) * 0.5f;

    float o0 = 0.0f, o1 = 0.0f;

#pragma unroll
    for (int level = 0; level < 3; ++level) {
        const float scale = (float)((128 << level) - 1);  // 127, 255, 511
        const float px = fmaf(x0, scale, 0.5f);
        const float py = fmaf(y0, scale, 0.5f);
        const float pz = fmaf(z0, scale, 0.5f);
        const float fx = floorf(px), fy = floorf(py), fz = floorf(pz);
        const float rx = px - fx, ry = py - fy, rz = pz - fz;
        const unsigned gx = (unsigned)fx, gy = (unsigned)fy, gz = (unsigned)fz;

        const float* __restrict__ base = triplane + level * (2 * PLANE);

        // hash of the 8 corners; uint32 mult wraps exactly like the reference
#pragma unroll
        for (int c = 0; c < 8; ++c) {
            const unsigned bx = (c >> 0) & 1;
            const unsigned by = (c >> 1) & 1;
            const unsigned bz = (c >> 2) & 1;
            const unsigned cx = gx + bx;
            const unsigned cy = gy + by;
            const unsigned cz = gz + bz;
            const unsigned h = cx ^ (cy * 2654435761u) ^ (cz * 805459861u);
            const unsigned local = h & HMASK;

            const float w = (bx ? rx : 1.0f - rx) *
                            (by ? ry : 1.0f - ry) *
                            (bz ? rz : 1.0f - rz);

            o0 = fmaf(w, base[local], o0);
            o1 = fmaf(w, base[PLANE + local], o1);
        }
    }

    // coalesced float2 store: out[i] = {o0, o1}
    reinterpret_cast<float2*>(out)[i] = make_float2(o0, o1);
}

extern "C" void kernel_launch(void* const* d_in, const int* in_sizes, int n_in,
                              void* d_out, int out_size, void* d_ws, size_t ws_size,
                              hipStream_t stream) {
    const float* triplane = (const float*)d_in[0];  // 3*2*1024*512 floats
    const float* inputs   = (const float*)d_in[1];  // B*3 floats
    float* out = (float*)d_out;                     // B*2 floats

    const int threads = 256;
    const int blocks = (NPOINTS + threads - 1) / threads;
    GridEncoder_74234214744826_kernel<<<blocks, threads, 0, stream>>>(triplane, inputs, out);
}

// Round 2
// 253.599 us; speedup vs baseline: 2.3138x; 2.3138x over previous
//
#include <hip/hip_runtime.h>
#include <hip/hip_fp16.h>

// GridEncoder (instant-NGP triplane hash grid), static config:
//   D=3, L=3, C=2, base_res=128, per_level_scale=2, hashmap=2^19,
//   align_corners=False, linear interp, B=2^21.
// All levels hash-index (stride^3 > 2^19); hmap=2^19 -> mod == & 0x7FFFF.
// emb[idx][c] == triplane_flat[l*2^20 + c*2^19 + (idx & 0x7FFFF)].
//
// R1 analysis: FETCH_SIZE 1.97 GB (50x over-fetch) — gathers miss L2 because
// the 12 MB table > 4 MiB/XCD L2 and channels are 2 MB apart (2 lines/corner).
// R2 strategy: (a) prepass packs table to half2 (both channels, 4B/corner,
// 6 MB total); (b) split by level into 3 launches so each pass's gather set
// is one 2 MB level-table, fully L2-resident per XCD; (c) non-temporal input
// loads to protect table residency.

#define NPOINTS  2097152
#define HMASK    0x7FFFFu
#define PLANE    524288            // elements per (level, channel) slice
#define NTAB     (3 * PLANE)       // packed half2 entries

// ---- prepass: fp32 [3][2][1024][512] -> half2 table [3][2^19] ----
__global__ __launch_bounds__(256) void tp_convert_kernel(
    const float* __restrict__ tp, unsigned* __restrict__ tbl)
{
    const unsigned t = blockIdx.x * 256u + threadIdx.x;   // < NTAB
    const unsigned level = t >> 19;
    const unsigned idx   = t & HMASK;
    const float* __restrict__ b = tp + level * (2u * PLANE);
    const __half2 h2 = __halves2half2(__float2half_rn(b[idx]),
                                      __float2half_rn(b[PLANE + idx]));
    tbl[t] = *reinterpret_cast<const unsigned*>(&h2);
}

// ---- per-level gather; FIRST writes, else accumulates ----
template <int LEVEL, bool FIRST>
__global__ __launch_bounds__(256) void grid_gather_kernel(
    const unsigned* __restrict__ tbl,
    const float* __restrict__ inputs,
    float2* __restrict__ out)
{
    const int i = blockIdx.x * 256 + threadIdx.x;

    // non-temporal: the coordinate stream has no reuse within a pass;
    // keep it from evicting the L2-resident level table.
    const float x = __builtin_nontemporal_load(&inputs[3 * i + 0]);
    const float y = __builtin_nontemporal_load(&inputs[3 * i + 1]);
    const float z = __builtin_nontemporal_load(&inputs[3 * i + 2]);

    const float scale = (float)((128 << LEVEL) - 1);      // 127, 255, 511
    const float px = fmaf((x + 1.0f) * 0.5f, scale, 0.5f);
    const float py = fmaf((y + 1.0f) * 0.5f, scale, 0.5f);
    const float pz = fmaf((z + 1.0f) * 0.5f, scale, 0.5f);
    const float fx = floorf(px), fy = floorf(py), fz = floorf(pz);
    const float rx = px - fx, ry = py - fy, rz = pz - fz;
    const unsigned gx = (unsigned)fx, gy = (unsigned)fy, gz = (unsigned)fz;

    const unsigned hy0 = gy * 2654435761u;
    const unsigned hy1 = (gy + 1u) * 2654435761u;
    const unsigned hz0 = gz * 805459861u;
    const unsigned hz1 = (gz + 1u) * 805459861u;
    const unsigned gx1 = gx + 1u;

    const unsigned* __restrict__ base = tbl + LEVEL * PLANE;

    // issue all 8 independent gathers up front (latency hiding)
    unsigned idxs[8];
    idxs[0] = (gx  ^ hy0 ^ hz0) & HMASK;
    idxs[1] = (gx1 ^ hy0 ^ hz0) & HMASK;
    idxs[2] = (gx  ^ hy1 ^ hz0) & HMASK;
    idxs[3] = (gx1 ^ hy1 ^ hz0) & HMASK;
    idxs[4] = (gx  ^ hy0 ^ hz1) & HMASK;
    idxs[5] = (gx1 ^ hy0 ^ hz1) & HMASK;
    idxs[6] = (gx  ^ hy1 ^ hz1) & HMASK;
    idxs[7] = (gx1 ^ hy1 ^ hz1) & HMASK;

    unsigned raw[8];
#pragma unroll
    for (int c = 0; c < 8; ++c) raw[c] = base[idxs[c]];

    const float wx1 = rx, wx0 = 1.0f - rx;
    const float wy1 = ry, wy0 = 1.0f - ry;
    const float wz1 = rz, wz0 = 1.0f - rz;
    const float w[8] = { wx0 * wy0 * wz0, wx1 * wy0 * wz0,
                         wx0 * wy1 * wz0, wx1 * wy1 * wz0,
                         wx0 * wy0 * wz1, wx1 * wy0 * wz1,
                         wx0 * wy1 * wz1, wx1 * wy1 * wz1 };

    float o0 = 0.0f, o1 = 0.0f;
#pragma unroll
    for (int c = 0; c < 8; ++c) {
        const __half2 h2 = *reinterpret_cast<const __half2*>(&raw[c]);
        const float2 f = __half22float2(h2);
        o0 = fmaf(w[c], f.x, o0);
        o1 = fmaf(w[c], f.y, o1);
    }

    if (FIRST) {
        out[i] = make_float2(o0, o1);
    } else {
        const float2 p = out[i];
        out[i] = make_float2(p.x + o0, p.y + o1);
    }
}

// ---- fallback (R1 kernel) if ws_size is too small for the packed table ----
__global__ __launch_bounds__(256) void grid_fallback_kernel(
    const float* __restrict__ triplane,
    const float* __restrict__ inputs,
    float* __restrict__ out)
{
    const int i = blockIdx.x * blockDim.x + threadIdx.x;
    if (i >= NPOINTS) return;
    const float x0 = (inputs[3 * i + 0] + 1.0f) * 0.5f;
    const float y0 = (inputs[3 * i + 1] + 1.0f) * 0.5f;
    const float z0 = (inputs[3 * i + 2] + 1.0f) * 0.5f;
    float o0 = 0.0f, o1 = 0.0f;
#pragma unroll
    for (int level = 0; level < 3; ++level) {
        const float scale = (float)((128 << level) - 1);
        const float px = fmaf(x0, scale, 0.5f);
        const float py = fmaf(y0, scale, 0.5f);
        const float pz = fmaf(z0, scale, 0.5f);
        const float fx = floorf(px), fy = floorf(py), fz = floorf(pz);
        const float rx = px - fx, ry = py - fy, rz = pz - fz;
        const unsigned gx = (unsigned)fx, gy = (unsigned)fy, gz = (unsigned)fz;
        const float* __restrict__ base = triplane + level * (2 * PLANE);
#pragma unroll
        for (int c = 0; c < 8; ++c) {
            const unsigned bx = (c >> 0) & 1, by = (c >> 1) & 1, bz = (c >> 2) & 1;
            const unsigned h = (gx + bx) ^ ((gy + by) * 2654435761u) ^ ((gz + bz) * 805459861u);
            const unsigned local = h & HMASK;
            const float w = (bx ? rx : 1.0f - rx) * (by ? ry : 1.0f - ry) * (bz ? rz : 1.0f - rz);
            o0 = fmaf(w, base[local], o0);
            o1 = fmaf(w, base[PLANE + local], o1);
        }
    }
    reinterpret_cast<float2*>(out)[i] = make_float2(o0, o1);
}

extern "C" void kernel_launch(void* const* d_in, const int* in_sizes, int n_in,
                              void* d_out, int out_size, void* d_ws, size_t ws_size,
                              hipStream_t stream) {
    const float* triplane = (const float*)d_in[0];  // 3*2*1024*512 fp32
    const float* inputs   = (const float*)d_in[1];  // B*3 fp32
    const int threads = 256;
    const int gblocks = NPOINTS / threads;          // 8192

    if (ws_size >= (size_t)NTAB * sizeof(unsigned)) {
        unsigned* tbl = (unsigned*)d_ws;
        float2* out = (float2*)d_out;
        tp_convert_kernel<<<NTAB / threads, threads, 0, stream>>>(triplane, tbl);
        grid_gather_kernel<0, true ><<<gblocks, threads, 0, stream>>>(tbl, inputs, out);
        grid_gather_kernel<1, false><<<gblocks, threads, 0, stream>>>(tbl, inputs, out);
        grid_gather_kernel<2, false><<<gblocks, threads, 0, stream>>>(tbl, inputs, out);
    } else {
        grid_fallback_kernel<<<gblocks, threads, 0, stream>>>(triplane, inputs, (float*)d_out);
    }
}

// Round 4
// 249.588 us; speedup vs baseline: 2.3510x; 1.0161x over previous
//
#include <hip/hip_runtime.h>
#include <hip/hip_fp16.h>

// GridEncoder (instant-NGP triplane hash grid), static config:
//   D=3, L=3, C=2, base_res=128, per_level_scale=2, hashmap=2^19,
//   align_corners=False, linear interp, B=2^21.
// All levels hash-index (stride^3 > 2^19); hmap=2^19 -> mod == & 0x7FFFF.
// emb[idx][c] == triplane_flat[l*2^20 + c*2^19 + (idx & 0x7FFFF)].
//
// R1: naive fp32 fused -> HBM-bound, FETCH 1.97 GB, 543 us.
// R2: half2-packed table + 3 level-split passes -> 254 us; each pass 62 us,
//     VALUBusy 6.6%, hbm 3-9% -> bound by random-request throughput/latency,
//     plus ~65 us of pass overhead (input re-reads, out RMW, kernel gaps).
// R3: fused single gather kernel (24 gathers in flight/thread). R3 failed
//     compile: __builtin_nontemporal_store rejects HIP_vector_type float2;
//     use a native ext_vector_type(2) instead.

#define NPOINTS  2097152
#define HMASK    0x7FFFFu
#define PLANE    524288            // elements per (level, channel) slice
#define NTAB     (3 * PLANE)       // packed half2 entries (6 MB)

typedef float floatx2 __attribute__((ext_vector_type(2)));

// ---- prepass: fp32 [3][2][1024][512] -> half2 table [3][2^19] ----
__global__ __launch_bounds__(256) void tp_convert_kernel(
    const float* __restrict__ tp, unsigned* __restrict__ tbl)
{
    const unsigned t = blockIdx.x * 256u + threadIdx.x;   // < NTAB
    const unsigned level = t >> 19;
    const unsigned idx   = t & HMASK;
    const float* __restrict__ b = tp + level * (2u * PLANE);
    const __half2 h2 = __halves2half2(__float2half_rn(b[idx]),
                                      __float2half_rn(b[PLANE + idx]));
    tbl[t] = *reinterpret_cast<const unsigned*>(&h2);
}

// ---- fused gather: all 3 levels, 24 independent gathers per point ----
__global__ __launch_bounds__(256) void grid_gather_kernel(
    const unsigned* __restrict__ tbl,
    const float* __restrict__ inputs,
    floatx2* __restrict__ out)
{
    const int i = blockIdx.x * 256 + threadIdx.x;

    // coordinate stream: no reuse — keep it out of the table's cache space
    const float x = __builtin_nontemporal_load(&inputs[3 * i + 0]);
    const float y = __builtin_nontemporal_load(&inputs[3 * i + 1]);
    const float z = __builtin_nontemporal_load(&inputs[3 * i + 2]);
    const float x0 = (x + 1.0f) * 0.5f;
    const float y0 = (y + 1.0f) * 0.5f;
    const float z0 = (z + 1.0f) * 0.5f;

    unsigned idxs[24];
    float rxs[3], rys[3], rzs[3];

#pragma unroll
    for (int level = 0; level < 3; ++level) {
        const float scale = (float)((128 << level) - 1);  // 127, 255, 511
        const float px = fmaf(x0, scale, 0.5f);
        const float py = fmaf(y0, scale, 0.5f);
        const float pz = fmaf(z0, scale, 0.5f);
        const float fx = floorf(px), fy = floorf(py), fz = floorf(pz);
        rxs[level] = px - fx; rys[level] = py - fy; rzs[level] = pz - fz;
        const unsigned gx = (unsigned)fx, gy = (unsigned)fy, gz = (unsigned)fz;

        const unsigned hy0 = gy * 2654435761u;
        const unsigned hy1 = (gy + 1u) * 2654435761u;
        const unsigned hz0 = gz * 805459861u;
        const unsigned hz1 = (gz + 1u) * 805459861u;
        const unsigned gx1 = gx + 1u;
        const unsigned lvl = (unsigned)level << 19;  // level * PLANE

        idxs[level * 8 + 0] = lvl + ((gx  ^ hy0 ^ hz0) & HMASK);
        idxs[level * 8 + 1] = lvl + ((gx1 ^ hy0 ^ hz0) & HMASK);
        idxs[level * 8 + 2] = lvl + ((gx  ^ hy1 ^ hz0) & HMASK);
        idxs[level * 8 + 3] = lvl + ((gx1 ^ hy1 ^ hz0) & HMASK);
        idxs[level * 8 + 4] = lvl + ((gx  ^ hy0 ^ hz1) & HMASK);
        idxs[level * 8 + 5] = lvl + ((gx1 ^ hy0 ^ hz1) & HMASK);
        idxs[level * 8 + 6] = lvl + ((gx  ^ hy1 ^ hz1) & HMASK);
        idxs[level * 8 + 7] = lvl + ((gx1 ^ hy1 ^ hz1) & HMASK);
    }

    // issue all 24 independent gathers before any consumption (max MLP)
    unsigned raw[24];
#pragma unroll
    for (int c = 0; c < 24; ++c) raw[c] = tbl[idxs[c]];

    float o0 = 0.0f, o1 = 0.0f;
#pragma unroll
    for (int level = 0; level < 3; ++level) {
        const float rx = rxs[level], ry = rys[level], rz = rzs[level];
        const float wx1 = rx, wx0 = 1.0f - rx;
        const float wy1 = ry, wy0 = 1.0f - ry;
        const float wz1 = rz, wz0 = 1.0f - rz;
        const float w[8] = { wx0 * wy0 * wz0, wx1 * wy0 * wz0,
                             wx0 * wy1 * wz0, wx1 * wy1 * wz0,
                             wx0 * wy0 * wz1, wx1 * wy0 * wz1,
                             wx0 * wy1 * wz1, wx1 * wy1 * wz1 };
#pragma unroll
        for (int c = 0; c < 8; ++c) {
            const __half2 h2 = *reinterpret_cast<const __half2*>(&raw[level * 8 + c]);
            const float2 f = __half22float2(h2);
            o0 = fmaf(w[c], f.x, o0);
            o1 = fmaf(w[c], f.y, o1);
        }
    }

    floatx2 r; r.x = o0; r.y = o1;
    __builtin_nontemporal_store(r, &out[i]);
}

// ---- fallback (R1 kernel) if ws_size is too small for the packed table ----
__global__ __launch_bounds__(256) void grid_fallback_kernel(
    const float* __restrict__ triplane,
    const float* __restrict__ inputs,
    float* __restrict__ out)
{
    const int i = blockIdx.x * blockDim.x + threadIdx.x;
    if (i >= NPOINTS) return;
    const float x0 = (inputs[3 * i + 0] + 1.0f) * 0.5f;
    const float y0 = (inputs[3 * i + 1] + 1.0f) * 0.5f;
    const float z0 = (inputs[3 * i + 2] + 1.0f) * 0.5f;
    float o0 = 0.0f, o1 = 0.0f;
#pragma unroll
    for (int level = 0; level < 3; ++level) {
        const float scale = (float)((128 << level) - 1);
        const float px = fmaf(x0, scale, 0.5f);
        const float py = fmaf(y0, scale, 0.5f);
        const float pz = fmaf(z0, scale, 0.5f);
        const float fx = floorf(px), fy = floorf(py), fz = floorf(pz);
        const float rx = px - fx, ry = py - fy, rz = pz - fz;
        const unsigned gx = (unsigned)fx, gy = (unsigned)fy, gz = (unsigned)fz;
        const float* __restrict__ base = triplane + level * (2 * PLANE);
#pragma unroll
        for (int c = 0; c < 8; ++c) {
            const unsigned bx = (c >> 0) & 1, by = (c >> 1) & 1, bz = (c >> 2) & 1;
            const unsigned h = (gx + bx) ^ ((gy + by) * 2654435761u) ^ ((gz + bz) * 805459861u);
            const unsigned local = h & HMASK;
            const float w = (bx ? rx : 1.0f - rx) * (by ? ry : 1.0f - ry) * (bz ? rz : 1.0f - rz);
            o0 = fmaf(w, base[local], o0);
            o1 = fmaf(w, base[PLANE + local], o1);
        }
    }
    reinterpret_cast<float2*>(out)[i] = make_float2(o0, o1);
}

extern "C" void kernel_launch(void* const* d_in, const int* in_sizes, int n_in,
                              void* d_out, int out_size, void* d_ws, size_t ws_size,
                              hipStream_t stream) {
    const float* triplane = (const float*)d_in[0];  // 3*2*1024*512 fp32
    const float* inputs   = (const float*)d_in[1];  // B*3 fp32
    const int threads = 256;
    const int gblocks = NPOINTS / threads;          // 8192

    if (ws_size >= (size_t)NTAB * sizeof(unsigned)) {
        unsigned* tbl = (unsigned*)d_ws;
        tp_convert_kernel<<<NTAB / threads, threads, 0, stream>>>(triplane, tbl);
        grid_gather_kernel<<<gblocks, threads, 0, stream>>>(tbl, inputs, (floatx2*)d_out);
    } else {
        grid_fallback_kernel<<<gblocks, threads, 0, stream>>>(triplane, inputs, (float*)d_out);
    }
}